// Round 1
// baseline (13141.415 us; speedup 1.0000x reference)
//
#include <hip/hip_runtime.h>
#include <math.h>

#define N_NODES 100000
#define N_EDGES 1200000
#define N_GRAPHS 256
#define CH 64
#define NC (N_NODES * CH)
#define EPS 1e-5f

// ---------------- embed: out = x @ W_in + b_in ----------------
__global__ void embed_kernel(const float* __restrict__ x,
                             const float* __restrict__ W,   // [12,64]
                             const float* __restrict__ b,   // [64]
                             float* __restrict__ out) {     // [N,64]
    int idx = blockIdx.x * blockDim.x + threadIdx.x;
    if (idx >= NC) return;
    int i = idx >> 6;
    int c = idx & 63;
    const float* xr = x + i * 12;
    float acc = b[c];
#pragma unroll
    for (int k = 0; k < 12; ++k)
        acc = fmaf(xr[k], W[k * CH + c], acc);
    out[idx] = acc;
}

// ---------------- BN stats: per-channel sum & sumsq over N ----------------
__global__ void bn_stats_kernel(const float* __restrict__ a,
                                float* __restrict__ stats) { // [128] pre-zeroed
    int c = threadIdx.x & 63;
    int sub = threadIdx.x >> 6;              // 0..3
    int rowStart = blockIdx.x * 4 + sub;
    int rowStride = gridDim.x * 4;
    float s = 0.f, q = 0.f;
    for (int r = rowStart; r < N_NODES; r += rowStride) {
        float v = a[r * CH + c];
        s += v;
        q = fmaf(v, v, q);
    }
    __shared__ float ls[4][64];
    __shared__ float lq[4][64];
    ls[sub][c] = s;
    lq[sub][c] = q;
    __syncthreads();
    if (sub == 0) {
        s = ls[0][c] + ls[1][c] + ls[2][c] + ls[3][c];
        q = lq[0][c] + lq[1][c] + lq[2][c] + lq[3][c];
        atomicAdd(&stats[c], s);
        atomicAdd(&stats[64 + c], q);
    }
}

// ---------------- BN finalize: scale/shift per channel ----------------
__global__ void bn_finalize_kernel(const float* __restrict__ stats,
                                   const float* __restrict__ gamma,
                                   const float* __restrict__ beta,
                                   float* __restrict__ ab) { // [128]: A then B
    int c = threadIdx.x; // 64 threads
    float mean = stats[c] * (1.0f / (float)N_NODES);
    float var  = stats[64 + c] * (1.0f / (float)N_NODES) - mean * mean;
    float inv  = rsqrtf(var + EPS);
    float A = gamma[c] * inv;
    ab[c] = A;
    ab[64 + c] = beta[c] - mean * A;
}

// ---------------- BN apply (+residual, +relu), in place on a ----------------
template <bool RELU, bool RES>
__global__ void bn_apply_kernel(float* __restrict__ a,
                                const float* __restrict__ res,
                                const float* __restrict__ ab) {
    int idx = blockIdx.x * blockDim.x + threadIdx.x;
    if (idx >= NC) return;
    int c = idx & 63;
    float v = fmaf(a[idx], ab[c], ab[64 + c]);
    if (RES) v += res[idx];
    if (RELU) v = fmaxf(v, 0.f);
    a[idx] = v;
}

// ---------------- CGConv edge kernel ----------------
// lane = edge; blockIdx.y = channel-group g (channels [g*32, g*32+32))
// Each lane accumulates 32 f-channels and 32 s-channels for its edge,
// then scatters m = sigmoid(f)*softplus(s) into agg[dst].
__global__ __launch_bounds__(256, 4)
void edge_kernel(const float* __restrict__ h,    // [N,64]
                 const int* __restrict__ ei,     // [2,E]: src then dst
                 const float* __restrict__ ea,   // [E]
                 const float* __restrict__ Wf,   // [129,64]
                 const float* __restrict__ bf,   // [64]
                 const float* __restrict__ Ws,   // [129,64]
                 const float* __restrict__ bs,   // [64]
                 float* __restrict__ agg) {      // [N,64] pre-zeroed
    const int lane = threadIdx.x & 63;
    const int wave = threadIdx.x >> 6;
    const int g = blockIdx.y;                    // 0 or 1
    const int e = blockIdx.x * 256 + wave * 64 + lane;
    const bool valid = (e < N_EDGES);
    const int ec = valid ? e : (N_EDGES - 1);

    const int src = ei[ec];
    const int dst = ei[N_EDGES + ec];
    const float eav = ea[ec];

    const float* Wfg = Wf + g * 32;
    const float* Wsg = Ws + g * 32;

    float accf[32], accs[32];
#pragma unroll
    for (int c = 0; c < 32; ++c) {
        accf[c] = bf[g * 32 + c];
        accs[c] = bs[g * 32 + c];
    }

    const float* hd = h + dst * CH;  // z[0:64]   = x[dst]
    const float* hs = h + src * CH;  // z[64:128] = x[src]

#pragma unroll 2
    for (int k = 0; k < 64; ++k) {
        float zk = hd[k];
        const float* wf = Wfg + k * CH;
        const float* ws = Wsg + k * CH;
#pragma unroll
        for (int c = 0; c < 32; ++c) {
            accf[c] = fmaf(zk, wf[c], accf[c]);
            accs[c] = fmaf(zk, ws[c], accs[c]);
        }
    }
#pragma unroll 2
    for (int k = 0; k < 64; ++k) {
        float zk = hs[k];
        const float* wf = Wfg + (64 + k) * CH;
        const float* ws = Wsg + (64 + k) * CH;
#pragma unroll
        for (int c = 0; c < 32; ++c) {
            accf[c] = fmaf(zk, wf[c], accf[c]);
            accs[c] = fmaf(zk, ws[c], accs[c]);
        }
    }
    {
        const float* wf = Wfg + 128 * CH;
        const float* ws = Wsg + 128 * CH;
#pragma unroll
        for (int c = 0; c < 32; ++c) {
            accf[c] = fmaf(eav, wf[c], accf[c]);
            accs[c] = fmaf(eav, ws[c], accs[c]);
        }
    }

    if (valid) {
        float* dp = agg + dst * CH + g * 32;
#pragma unroll
        for (int c = 0; c < 32; ++c) {
            float f = accf[c];
            float s = accs[c];
            float sig = 1.0f / (1.0f + __expf(-f));
            float sp  = fmaxf(s, 0.0f) + log1pf(__expf(-fabsf(s)));
            atomicAdd(dp + c, sig * sp);
        }
    }
}

// ---------------- global mean pool (scatter-add) ----------------
__global__ void pool_kernel(const float* __restrict__ h,
                            const int* __restrict__ batch,
                            float* __restrict__ pooled,   // [G,64] pre-zeroed
                            float* __restrict__ counts) { // [G]   pre-zeroed
    int idx = blockIdx.x * blockDim.x + threadIdx.x;
    if (idx >= NC) return;
    int i = idx >> 6;
    int c = idx & 63;
    int b = batch[i];
    atomicAdd(&pooled[b * CH + c], h[idx]);
    if (c == 0) atomicAdd(&counts[b], 1.0f);
}

// ---------------- head: relu(pooled/cnt @ W1 + b1) @ W2 + b2 ----------------
__global__ void head_kernel(const float* __restrict__ pooled,
                            const float* __restrict__ counts,
                            const float* __restrict__ W1,  // [64,32]
                            const float* __restrict__ b1,  // [32]
                            const float* __restrict__ W2,  // [32]
                            const float* __restrict__ b2,  // [1]
                            float* __restrict__ out) {     // [G]
    int gph = blockIdx.x;
    int t = threadIdx.x;  // 64 threads
    __shared__ float p[64];
    __shared__ float h1[32];
    float cnt = fmaxf(counts[gph], 1.0f);
    p[t] = pooled[gph * CH + t] / cnt;
    __syncthreads();
    if (t < 32) {
        float acc = b1[t];
#pragma unroll
        for (int c = 0; c < 64; ++c)
            acc = fmaf(p[c], W1[c * 32 + t], acc);
        h1[t] = fmaxf(acc, 0.0f);
    }
    __syncthreads();
    if (t == 0) {
        float acc = b2[0];
#pragma unroll
        for (int j = 0; j < 32; ++j)
            acc = fmaf(h1[j], W2[j], acc);
        out[gph] = acc;
    }
}

extern "C" void kernel_launch(void* const* d_in, const int* in_sizes, int n_in,
                              void* d_out, int out_size, void* d_ws, size_t ws_size,
                              hipStream_t stream) {
    const float* x     = (const float*)d_in[0];
    const int*   ei    = (const int*)d_in[1];
    const float* ea    = (const float*)d_in[2];
    const int*   batch = (const int*)d_in[3];
    const float* W_in  = (const float*)d_in[4];
    const float* b_in  = (const float*)d_in[5];
    const float* g0    = (const float*)d_in[6];
    const float* beta0 = (const float*)d_in[7];

    const float* Wf[3] = {(const float*)d_in[8],  (const float*)d_in[14], (const float*)d_in[20]};
    const float* bf[3] = {(const float*)d_in[9],  (const float*)d_in[15], (const float*)d_in[21]};
    const float* Ws[3] = {(const float*)d_in[10], (const float*)d_in[16], (const float*)d_in[22]};
    const float* bs[3] = {(const float*)d_in[11], (const float*)d_in[17], (const float*)d_in[23]};
    const float* gm[3] = {(const float*)d_in[12], (const float*)d_in[18], (const float*)d_in[24]};
    const float* bb[3] = {(const float*)d_in[13], (const float*)d_in[19], (const float*)d_in[25]};

    const float* W1 = (const float*)d_in[26];
    const float* b1 = (const float*)d_in[27];
    const float* W2 = (const float*)d_in[28];
    const float* b2 = (const float*)d_in[29];

    float* out = (float*)d_out;

    float* ws     = (float*)d_ws;
    float* hA     = ws;                 // [N,64]
    float* hB     = ws + NC;            // [N,64]
    float* stats  = ws + 2 * (size_t)NC; // [128] sum/sumsq
    float* ab     = stats + 128;        // [128] scale/shift
    float* pooled = stats + 256;        // [G,64]
    float* counts = pooled + N_GRAPHS * CH; // [G]

    const int elemBlocks = (NC + 255) / 256;

    // ---- input embedding + BN0 + relu ----
    embed_kernel<<<elemBlocks, 256, 0, stream>>>(x, W_in, b_in, hA);
    hipMemsetAsync(stats, 0, 128 * sizeof(float), stream);
    bn_stats_kernel<<<512, 256, 0, stream>>>(hA, stats);
    bn_finalize_kernel<<<1, 64, 0, stream>>>(stats, g0, beta0, ab);
    bn_apply_kernel<true, false><<<elemBlocks, 256, 0, stream>>>(hA, nullptr, ab);

    float* hcur = hA;
    float* hnext = hB;
    dim3 egrid((N_EDGES + 255) / 256, 2);

    for (int l = 0; l < 3; ++l) {
        hipMemsetAsync(hnext, 0, (size_t)NC * sizeof(float), stream);
        hipMemsetAsync(stats, 0, 128 * sizeof(float), stream);
        edge_kernel<<<egrid, 256, 0, stream>>>(hcur, ei, ea, Wf[l], bf[l], Ws[l], bs[l], hnext);
        bn_stats_kernel<<<512, 256, 0, stream>>>(hnext, stats);
        bn_finalize_kernel<<<1, 64, 0, stream>>>(stats, gm[l], bb[l], ab);
        if (l < 2)
            bn_apply_kernel<true, true><<<elemBlocks, 256, 0, stream>>>(hnext, hcur, ab);
        else
            bn_apply_kernel<false, true><<<elemBlocks, 256, 0, stream>>>(hnext, hcur, ab);
        float* tmp = hcur; hcur = hnext; hnext = tmp;
    }

    // ---- pool + head ----
    hipMemsetAsync(pooled, 0, (size_t)(N_GRAPHS * CH + N_GRAPHS) * sizeof(float), stream);
    pool_kernel<<<elemBlocks, 256, 0, stream>>>(hcur, batch, pooled, counts);
    head_kernel<<<N_GRAPHS, 64, 0, stream>>>(pooled, counts, W1, b1, W2, b2, out);
}

// Round 2
// 2999.279 us; speedup vs baseline: 4.3815x; 4.3815x over previous
//
#include <hip/hip_runtime.h>
#include <math.h>

#define N_NODES 100000
#define N_EDGES 1200000
#define N_GRAPHS 256
#define CH 64
#define NC (N_NODES * CH)
#define EPS 1e-5f

// ---------------- embed: out = x @ W_in + b_in ----------------
__global__ void embed_kernel(const float* __restrict__ x,
                             const float* __restrict__ W,   // [12,64]
                             const float* __restrict__ b,   // [64]
                             float* __restrict__ out) {     // [N,64]
    int idx = blockIdx.x * blockDim.x + threadIdx.x;
    if (idx >= NC) return;
    int i = idx >> 6;
    int c = idx & 63;
    const float* xr = x + i * 12;
    float acc = b[c];
#pragma unroll
    for (int k = 0; k < 12; ++k)
        acc = fmaf(xr[k], W[k * CH + c], acc);
    out[idx] = acc;
}

// ---------------- BN stats: per-channel sum & sumsq over N ----------------
__global__ void bn_stats_kernel(const float* __restrict__ a,
                                float* __restrict__ stats) { // [128] pre-zeroed
    int c = threadIdx.x & 63;
    int sub = threadIdx.x >> 6;              // 0..3
    int rowStart = blockIdx.x * 4 + sub;
    int rowStride = gridDim.x * 4;
    float s = 0.f, q = 0.f;
    for (int r = rowStart; r < N_NODES; r += rowStride) {
        float v = a[r * CH + c];
        s += v;
        q = fmaf(v, v, q);
    }
    __shared__ float ls[4][64];
    __shared__ float lq[4][64];
    ls[sub][c] = s;
    lq[sub][c] = q;
    __syncthreads();
    if (sub == 0) {
        s = ls[0][c] + ls[1][c] + ls[2][c] + ls[3][c];
        q = lq[0][c] + lq[1][c] + lq[2][c] + lq[3][c];
        atomicAdd(&stats[c], s);
        atomicAdd(&stats[64 + c], q);
    }
}

// ---------------- BN finalize: scale/shift per channel ----------------
__global__ void bn_finalize_kernel(const float* __restrict__ stats,
                                   const float* __restrict__ gamma,
                                   const float* __restrict__ beta,
                                   float* __restrict__ ab) { // [128]: A then B
    int c = threadIdx.x; // 64 threads
    float mean = stats[c] * (1.0f / (float)N_NODES);
    float var  = stats[64 + c] * (1.0f / (float)N_NODES) - mean * mean;
    float inv  = rsqrtf(var + EPS);
    float A = gamma[c] * inv;
    ab[c] = A;
    ab[64 + c] = beta[c] - mean * A;
}

// ---------------- BN apply (+residual, +relu), in place on a ----------------
template <bool RELU, bool RES>
__global__ void bn_apply_kernel(float* __restrict__ a,
                                const float* __restrict__ res,
                                const float* __restrict__ ab) {
    int idx = blockIdx.x * blockDim.x + threadIdx.x;
    if (idx >= NC) return;
    int c = idx & 63;
    float v = fmaf(a[idx], ab[c], ab[64 + c]);
    if (RES) v += res[idx];
    if (RELU) v = fmaxf(v, 0.f);
    a[idx] = v;
}

// ---------------- counting sort of edges by dst ----------------
__global__ void hist_kernel(const int* __restrict__ ei,
                            int* __restrict__ rowptr) { // [N+1] pre-zeroed
    int e = blockIdx.x * blockDim.x + threadIdx.x;
    if (e < N_EDGES) atomicAdd(&rowptr[ei[N_EDGES + e] + 1], 1);
}

// single-block inclusive scan over rowptr[0..N]; cursor[i] = scanned[i] (start offsets)
__global__ void scan_kernel(int* __restrict__ a, int* __restrict__ cursor) {
    __shared__ int wsum[16];
    __shared__ int carryS;
    int t = threadIdx.x;           // 1024 threads = 16 waves
    int lane = t & 63, w = t >> 6;
    if (t == 0) carryS = 0;
    __syncthreads();
    for (int base = 0; base <= N_NODES; base += 1024) {
        int i = base + t;
        int v = (i <= N_NODES) ? a[i] : 0;
        int s = v;
#pragma unroll
        for (int d = 1; d < 64; d <<= 1) {
            int o = __shfl_up(s, d);
            if (lane >= d) s += o;
        }
        if (lane == 63) wsum[w] = s;
        __syncthreads();
        if (w == 0) {
            int ws2 = (lane < 16) ? wsum[lane] : 0;
#pragma unroll
            for (int d = 1; d < 16; d <<= 1) {
                int o = __shfl_up(ws2, d);
                if (lane >= d) ws2 += o;
            }
            if (lane < 16) wsum[lane] = ws2;
        }
        __syncthreads();
        int waveoff = (w > 0) ? wsum[w - 1] : 0;
        int total = wsum[15];
        int res = s + waveoff + carryS;
        if (i <= N_NODES) {
            a[i] = res;
            if (i < N_NODES) cursor[i] = res;
        }
        __syncthreads();
        if (t == 0) carryS += total;
        __syncthreads();
    }
}

__global__ void scatter_kernel(const int* __restrict__ ei,
                               const float* __restrict__ ea,
                               int* __restrict__ cursor,
                               int* __restrict__ sdst,
                               int* __restrict__ ssrc,
                               float* __restrict__ sea) {
    int e = blockIdx.x * blockDim.x + threadIdx.x;
    if (e >= N_EDGES) return;
    int d = ei[N_EDGES + e];
    int pos = atomicAdd(&cursor[d], 1);
    sdst[pos] = d;
    ssrc[pos] = ei[e];
    sea[pos] = ea[e];
}

// ---------------- CGConv edge kernel (sorted edges) ----------------
// block = 512 threads = 8 waves, covers 64 sorted edges.
// z tile staged transposed in LDS: zT[k][edge], conflict-free reads.
// wave cg owns output columns [cg*8, cg*8+8) for BOTH lin_f and lin_s
// (16 fp32 accumulators / lane, weights via wave-uniform s_loads).
// Aggregation: segmented shuffle-scan over sorted-dst runs; only run-tail
// lanes issue global atomics.
__global__ __launch_bounds__(512, 8)
void edge_kernel(const float* __restrict__ h,     // [N,64]
                 const int* __restrict__ sdst,    // [E] sorted
                 const int* __restrict__ ssrc,    // [E]
                 const float* __restrict__ sea,   // [E]
                 const float* __restrict__ Wf,    // [129,64]
                 const float* __restrict__ bf,    // [64]
                 const float* __restrict__ Ws,    // [129,64]
                 const float* __restrict__ bs,    // [64]
                 float* __restrict__ agg) {       // [N,64] pre-zeroed
    __shared__ float zT[129][64];
    const int t = threadIdx.x;
    const int lane = t & 63;
    const int base = blockIdx.x * 64;

    // ---- stage z tile ----
    {
        const int e = lane;
        const int c = t >> 6;                    // wave id, 0..7 (uniform per wave)
        const int dstRow = sdst[base + e];
        const int srcRow = ssrc[base + e];
#pragma unroll
        for (int p = 0; p < 4; ++p) {
            int chunk = p * 8 + c;               // 0..31
            const float* rp = (chunk < 16) ? (h + dstRow * CH + chunk * 4)
                                           : (h + srcRow * CH + (chunk - 16) * 4);
            float4 v = *(const float4*)rp;
            int k0 = chunk * 4;                  // 0..124 (dst occupies 0..63, src 64..127)
            zT[k0 + 0][e] = v.x;
            zT[k0 + 1][e] = v.y;
            zT[k0 + 2][e] = v.z;
            zT[k0 + 3][e] = v.w;
        }
        if (c == 0) zT[128][e] = sea[base + e];
    }
    __syncthreads();

    const int cg = __builtin_amdgcn_readfirstlane(t >> 6);  // force wave-uniform
    const int col0 = cg * 8;
    const float* __restrict__ WfP = Wf + col0;
    const float* __restrict__ WsP = Ws + col0;

    float accf[8], accs[8];
#pragma unroll
    for (int j = 0; j < 8; ++j) {
        accf[j] = bf[col0 + j];
        accs[j] = bs[col0 + j];
    }

#pragma unroll 4
    for (int k = 0; k < 129; ++k) {
        float zk = zT[k][lane];
        const float* wf = WfP + k * CH;
        const float* ws = WsP + k * CH;
#pragma unroll
        for (int j = 0; j < 8; ++j) {
            accf[j] = fmaf(zk, wf[j], accf[j]);
            accs[j] = fmaf(zk, ws[j], accs[j]);
        }
    }

    // ---- activation: m = sigmoid(f) * softplus(s) ----
    float m[8];
#pragma unroll
    for (int j = 0; j < 8; ++j) {
        float sig = 1.0f / (1.0f + __expf(-accf[j]));
        float s = accs[j];
        float sp = fmaxf(s, 0.0f) + log1pf(__expf(-fabsf(s)));
        m[j] = sig * sp;
    }

    // ---- segmented reduction over sorted-dst runs within the wave ----
    const int mydst = sdst[base + lane];
    bool match[6];
#pragma unroll
    for (int s = 0; s < 6; ++s) {
        int d = 1 << s;
        int od = __shfl_up(mydst, d);
        match[s] = (lane >= d) && (od == mydst);
    }
#pragma unroll
    for (int j = 0; j < 8; ++j) {
        float v = m[j];
#pragma unroll
        for (int s = 0; s < 6; ++s) {
            float o = __shfl_up(v, 1 << s);
            if (match[s]) v += o;
        }
        m[j] = v;
    }
    int nd = __shfl_down(mydst, 1);
    bool tail = (lane == 63) || (nd != mydst);
    if (tail) {
        float* dp = agg + mydst * CH + col0;
#pragma unroll
        for (int j = 0; j < 8; ++j) atomicAdd(dp + j, m[j]);
    }
}

// ---------------- global mean pool (scatter-add) ----------------
__global__ void pool_kernel(const float* __restrict__ h,
                            const int* __restrict__ batch,
                            float* __restrict__ pooled,   // [G,64] pre-zeroed
                            float* __restrict__ counts) { // [G]   pre-zeroed
    int idx = blockIdx.x * blockDim.x + threadIdx.x;
    if (idx >= NC) return;
    int i = idx >> 6;
    int c = idx & 63;
    int b = batch[i];
    atomicAdd(&pooled[b * CH + c], h[idx]);
    if (c == 0) atomicAdd(&counts[b], 1.0f);
}

// ---------------- head ----------------
__global__ void head_kernel(const float* __restrict__ pooled,
                            const float* __restrict__ counts,
                            const float* __restrict__ W1,  // [64,32]
                            const float* __restrict__ b1,  // [32]
                            const float* __restrict__ W2,  // [32]
                            const float* __restrict__ b2,  // [1]
                            float* __restrict__ out) {     // [G]
    int gph = blockIdx.x;
    int t = threadIdx.x;  // 64 threads
    __shared__ float p[64];
    __shared__ float h1[32];
    float cnt = fmaxf(counts[gph], 1.0f);
    p[t] = pooled[gph * CH + t] / cnt;
    __syncthreads();
    if (t < 32) {
        float acc = b1[t];
#pragma unroll
        for (int c = 0; c < 64; ++c)
            acc = fmaf(p[c], W1[c * 32 + t], acc);
        h1[t] = fmaxf(acc, 0.0f);
    }
    __syncthreads();
    if (t == 0) {
        float acc = b2[0];
#pragma unroll
        for (int j = 0; j < 32; ++j)
            acc = fmaf(h1[j], W2[j], acc);
        out[gph] = acc;
    }
}

extern "C" void kernel_launch(void* const* d_in, const int* in_sizes, int n_in,
                              void* d_out, int out_size, void* d_ws, size_t ws_size,
                              hipStream_t stream) {
    const float* x     = (const float*)d_in[0];
    const int*   ei    = (const int*)d_in[1];
    const float* ea    = (const float*)d_in[2];
    const int*   batch = (const int*)d_in[3];
    const float* W_in  = (const float*)d_in[4];
    const float* b_in  = (const float*)d_in[5];
    const float* g0    = (const float*)d_in[6];
    const float* beta0 = (const float*)d_in[7];

    const float* Wf[3] = {(const float*)d_in[8],  (const float*)d_in[14], (const float*)d_in[20]};
    const float* bfv[3]= {(const float*)d_in[9],  (const float*)d_in[15], (const float*)d_in[21]};
    const float* Wsv[3]= {(const float*)d_in[10], (const float*)d_in[16], (const float*)d_in[22]};
    const float* bsv[3]= {(const float*)d_in[11], (const float*)d_in[17], (const float*)d_in[23]};
    const float* gm[3] = {(const float*)d_in[12], (const float*)d_in[18], (const float*)d_in[24]};
    const float* bb[3] = {(const float*)d_in[13], (const float*)d_in[19], (const float*)d_in[25]};

    const float* W1 = (const float*)d_in[26];
    const float* b1 = (const float*)d_in[27];
    const float* W2 = (const float*)d_in[28];
    const float* b2 = (const float*)d_in[29];

    float* out = (float*)d_out;

    float* ws     = (float*)d_ws;
    float* hA     = ws;                       // [N,64]
    float* hB     = hA + NC;                  // [N,64]
    float* stats  = hB + NC;                  // [128]
    float* ab     = stats + 128;              // [128]
    float* pooled = ab + 128;                 // [G,64]
    float* counts = pooled + N_GRAPHS * CH;   // [G]
    int*   rowptr = (int*)(counts + N_GRAPHS);        // [N+1]
    int*   cursor = rowptr + (N_NODES + 1);           // [N]
    int*   sdst   = cursor + N_NODES;                 // [E]
    int*   ssrc   = sdst + N_EDGES;                   // [E]
    float* sea    = (float*)(ssrc + N_EDGES);         // [E]

    const int elemBlocks = (NC + 255) / 256;
    const int edgeBlocks = (N_EDGES + 255) / 256;

    // ---- sort edges by dst (counting sort) ----
    hipMemsetAsync(rowptr, 0, (N_NODES + 1) * sizeof(int), stream);
    hist_kernel<<<edgeBlocks, 256, 0, stream>>>(ei, rowptr);
    scan_kernel<<<1, 1024, 0, stream>>>(rowptr, cursor);
    scatter_kernel<<<edgeBlocks, 256, 0, stream>>>(ei, ea, cursor, sdst, ssrc, sea);

    // ---- input embedding + BN0 + relu ----
    embed_kernel<<<elemBlocks, 256, 0, stream>>>(x, W_in, b_in, hA);
    hipMemsetAsync(stats, 0, 128 * sizeof(float), stream);
    bn_stats_kernel<<<512, 256, 0, stream>>>(hA, stats);
    bn_finalize_kernel<<<1, 64, 0, stream>>>(stats, g0, beta0, ab);
    bn_apply_kernel<true, false><<<elemBlocks, 256, 0, stream>>>(hA, nullptr, ab);

    float* hcur = hA;
    float* hnext = hB;

    for (int l = 0; l < 3; ++l) {
        hipMemsetAsync(hnext, 0, (size_t)NC * sizeof(float), stream);
        hipMemsetAsync(stats, 0, 128 * sizeof(float), stream);
        edge_kernel<<<N_EDGES / 64, 512, 0, stream>>>(hcur, sdst, ssrc, sea,
                                                      Wf[l], bfv[l], Wsv[l], bsv[l], hnext);
        bn_stats_kernel<<<512, 256, 0, stream>>>(hnext, stats);
        bn_finalize_kernel<<<1, 64, 0, stream>>>(stats, gm[l], bb[l], ab);
        if (l < 2)
            bn_apply_kernel<true, true><<<elemBlocks, 256, 0, stream>>>(hnext, hcur, ab);
        else
            bn_apply_kernel<false, true><<<elemBlocks, 256, 0, stream>>>(hnext, hcur, ab);
        float* tmp = hcur; hcur = hnext; hnext = tmp;
    }

    // ---- pool + head ----
    hipMemsetAsync(pooled, 0, (size_t)(N_GRAPHS * CH + N_GRAPHS) * sizeof(float), stream);
    pool_kernel<<<elemBlocks, 256, 0, stream>>>(hcur, batch, pooled, counts);
    head_kernel<<<N_GRAPHS, 64, 0, stream>>>(pooled, counts, W1, b1, W2, b2, out);
}

// Round 3
// 2345.102 us; speedup vs baseline: 5.6038x; 1.2790x over previous
//
#include <hip/hip_runtime.h>
#include <math.h>

#define N_NODES 100000
#define N_EDGES 1200000
#define N_GRAPHS 256
#define CH 64
#define NC (N_NODES * CH)
#define EPS 1e-5f

#define ZSTR 136   // f16 units per Z row (64 edges x 128+pad), 272B = 17*16B
#define ASTR 65    // f32 units per aggL row
#define NTILES (N_EDGES / 64)

typedef _Float16 half8 __attribute__((ext_vector_type(8)));
typedef float floatx4 __attribute__((ext_vector_type(4)));

// ---------------- embed: out = x @ W_in + b_in ----------------
__global__ void embed_kernel(const float* __restrict__ x,
                             const float* __restrict__ W,   // [12,64]
                             const float* __restrict__ b,   // [64]
                             float* __restrict__ out) {     // [N,64]
    int idx = blockIdx.x * blockDim.x + threadIdx.x;
    if (idx >= NC) return;
    int i = idx >> 6;
    int c = idx & 63;
    const float* xr = x + i * 12;
    float acc = b[c];
#pragma unroll
    for (int k = 0; k < 12; ++k)
        acc = fmaf(xr[k], W[k * CH + c], acc);
    out[idx] = acc;
}

// ---------------- BN stats ----------------
__global__ void bn_stats_kernel(const float* __restrict__ a,
                                float* __restrict__ stats) { // [128] pre-zeroed
    int c = threadIdx.x & 63;
    int sub = threadIdx.x >> 6;
    int rowStart = blockIdx.x * 4 + sub;
    int rowStride = gridDim.x * 4;
    float s = 0.f, q = 0.f;
    for (int r = rowStart; r < N_NODES; r += rowStride) {
        float v = a[r * CH + c];
        s += v;
        q = fmaf(v, v, q);
    }
    __shared__ float ls[4][64];
    __shared__ float lq[4][64];
    ls[sub][c] = s;
    lq[sub][c] = q;
    __syncthreads();
    if (sub == 0) {
        s = ls[0][c] + ls[1][c] + ls[2][c] + ls[3][c];
        q = lq[0][c] + lq[1][c] + lq[2][c] + lq[3][c];
        atomicAdd(&stats[c], s);
        atomicAdd(&stats[64 + c], q);
    }
}

// ---------------- BN finalize ----------------
__global__ void bn_finalize_kernel(const float* __restrict__ stats,
                                   const float* __restrict__ gamma,
                                   const float* __restrict__ beta,
                                   float* __restrict__ ab) { // [128]: A then B
    int c = threadIdx.x; // 64
    float mean = stats[c] * (1.0f / (float)N_NODES);
    float var  = stats[64 + c] * (1.0f / (float)N_NODES) - mean * mean;
    float inv  = rsqrtf(var + EPS);
    float A = gamma[c] * inv;
    ab[c] = A;
    ab[64 + c] = beta[c] - mean * A;
}

// ---------------- BN apply (+residual, +relu), in place ----------------
template <bool RELU, bool RES>
__global__ void bn_apply_kernel(float* __restrict__ a,
                                const float* __restrict__ res,
                                const float* __restrict__ ab) {
    int idx = blockIdx.x * blockDim.x + threadIdx.x;
    if (idx >= NC) return;
    int c = idx & 63;
    float v = fmaf(a[idx], ab[c], ab[64 + c]);
    if (RES) v += res[idx];
    if (RELU) v = fmaxf(v, 0.f);
    a[idx] = v;
}

// ---------------- counting sort of edges by dst ----------------
__global__ void hist_kernel(const int* __restrict__ ei,
                            int* __restrict__ rowptr) { // [N+1] pre-zeroed
    int e = blockIdx.x * blockDim.x + threadIdx.x;
    if (e < N_EDGES) atomicAdd(&rowptr[ei[N_EDGES + e] + 1], 1);
}

__global__ void scan_kernel(int* __restrict__ a, int* __restrict__ cursor) {
    __shared__ int wsum[16];
    __shared__ int carryS;
    int t = threadIdx.x;           // 1024 threads = 16 waves
    int lane = t & 63, w = t >> 6;
    if (t == 0) carryS = 0;
    __syncthreads();
    for (int base = 0; base <= N_NODES; base += 1024) {
        int i = base + t;
        int v = (i <= N_NODES) ? a[i] : 0;
        int s = v;
#pragma unroll
        for (int d = 1; d < 64; d <<= 1) {
            int o = __shfl_up(s, d);
            if (lane >= d) s += o;
        }
        if (lane == 63) wsum[w] = s;
        __syncthreads();
        if (w == 0) {
            int ws2 = (lane < 16) ? wsum[lane] : 0;
#pragma unroll
            for (int d = 1; d < 16; d <<= 1) {
                int o = __shfl_up(ws2, d);
                if (lane >= d) ws2 += o;
            }
            if (lane < 16) wsum[lane] = ws2;
        }
        __syncthreads();
        int waveoff = (w > 0) ? wsum[w - 1] : 0;
        int total = wsum[15];
        int res = s + waveoff + carryS;
        if (i <= N_NODES) {
            a[i] = res;
            if (i < N_NODES) cursor[i] = res;
        }
        __syncthreads();
        if (t == 0) carryS += total;
        __syncthreads();
    }
}

__global__ void scatter_kernel(const int* __restrict__ ei,
                               const float* __restrict__ ea,
                               int* __restrict__ cursor,
                               int* __restrict__ sdst,
                               int* __restrict__ ssrc,
                               float* __restrict__ sea) {
    int e = blockIdx.x * blockDim.x + threadIdx.x;
    if (e >= N_EDGES) return;
    int d = ei[N_EDGES + e];
    int pos = atomicAdd(&cursor[d], 1);
    sdst[pos] = d;
    ssrc[pos] = ei[e];
    sea[pos] = ea[e];
}

// ---------------- weight prep: WT[n][k] = W[k][n] in f16 ----------------
// WT rows 0..63 = Wf columns, 64..127 = Ws columns; k = 0..127.
// w128[128]: row-128 weights (edge_attr), bias[128]: bf|bs.
__global__ void prep_weights_kernel(const float* __restrict__ Wf,  // [129,64]
                                    const float* __restrict__ Ws,  // [129,64]
                                    const float* __restrict__ bf,
                                    const float* __restrict__ bs,
                                    _Float16* __restrict__ WT,     // [128,128]
                                    float* __restrict__ w128,      // [128]
                                    float* __restrict__ bias) {    // [128]
    int idx = blockIdx.x * blockDim.x + threadIdx.x;  // 16384
    if (idx < 128 * 128) {
        int n = idx >> 7;
        int k = idx & 127;
        float v = (n < 64) ? Wf[k * 64 + n] : Ws[k * 64 + (n - 64)];
        WT[idx] = (_Float16)v;
    }
    if (idx < 128) {
        w128[idx] = (idx < 64) ? Wf[128 * 64 + idx] : Ws[128 * 64 + (idx - 64)];
        bias[idx] = (idx < 64) ? bf[idx] : bs[idx - 64];
    }
}

// ---------------- CGConv edge kernel: f16 MFMA, persistent weights ----------
// 256 threads = 4 waves. Wave w computes 16 edges (rows w*16..+16) x 128 cols
// (4 f-tiles + 4 s-tiles of 16x16). B-frags (whole 128x128 W) resident in
// 128 VGPRs, loaded once per block. Grid-stride over 64-edge tiles.
__global__ __launch_bounds__(256, 2)
void edge_mfma_kernel(const float* __restrict__ h,     // [N,64] fp32
                      const int* __restrict__ sdst,    // [E] sorted
                      const int* __restrict__ ssrc,
                      const float* __restrict__ sea,
                      const _Float16* __restrict__ WT, // [128,128]
                      const float* __restrict__ w128,  // [128]
                      const float* __restrict__ bias,  // [128]
                      float* __restrict__ agg) {       // [N,64] pre-zeroed
    __shared__ __align__(16) _Float16 Zs[64 * ZSTR];
    __shared__ __align__(16) float aggL[64 * ASTR];
    __shared__ int dstL[64];
    __shared__ int lidxL[64];
    __shared__ int dstlist[64];
    __shared__ float eaL[64];
    __shared__ int ndistS;

    const int t = threadIdx.x;
    const int lane = t & 63;
    const int w = t >> 6;          // wave 0..3
    const int l15 = lane & 15;
    const int quad = lane >> 4;    // 0..3

    // ---- one-time: load all B-fragments + per-lane col constants ----
    half8 bfrag[8][4];
#pragma unroll
    for (int tt = 0; tt < 8; ++tt)
#pragma unroll
        for (int ks = 0; ks < 4; ++ks)
            bfrag[tt][ks] = *(const half8*)(WT + (tt * 16 + l15) * 128 + ks * 32 + quad * 8);

    float biasf[4], biass[4], wf128[4], ws128[4];
#pragma unroll
    for (int tt = 0; tt < 4; ++tt) {
        biasf[tt] = bias[tt * 16 + l15];
        biass[tt] = bias[64 + tt * 16 + l15];
        wf128[tt] = w128[tt * 16 + l15];
        ws128[tt] = w128[64 + tt * 16 + l15];
    }

    for (int tile = blockIdx.x; tile < NTILES; tile += gridDim.x) {
        const int base = tile * 64;

        // ---- stage Z (fp32 gather -> f16 LDS) ----
        {
            const int e = t >> 2, q = t & 3;
            const int dr = sdst[base + e];
            const int sr = ssrc[base + e];
            const float4* pd = (const float4*)(h + dr * 64 + q * 16);
            const float4* ps = (const float4*)(h + sr * 64 + q * 16);
            float4 d0 = pd[0], d1 = pd[1], d2 = pd[2], d3 = pd[3];
            float4 s0 = ps[0], s1 = ps[1], s2 = ps[2], s3 = ps[3];
            half8 o;
            o[0] = (_Float16)d0.x; o[1] = (_Float16)d0.y; o[2] = (_Float16)d0.z; o[3] = (_Float16)d0.w;
            o[4] = (_Float16)d1.x; o[5] = (_Float16)d1.y; o[6] = (_Float16)d1.z; o[7] = (_Float16)d1.w;
            *(half8*)(Zs + e * ZSTR + q * 16) = o;
            o[0] = (_Float16)d2.x; o[1] = (_Float16)d2.y; o[2] = (_Float16)d2.z; o[3] = (_Float16)d2.w;
            o[4] = (_Float16)d3.x; o[5] = (_Float16)d3.y; o[6] = (_Float16)d3.z; o[7] = (_Float16)d3.w;
            *(half8*)(Zs + e * ZSTR + q * 16 + 8) = o;
            o[0] = (_Float16)s0.x; o[1] = (_Float16)s0.y; o[2] = (_Float16)s0.z; o[3] = (_Float16)s0.w;
            o[4] = (_Float16)s1.x; o[5] = (_Float16)s1.y; o[6] = (_Float16)s1.z; o[7] = (_Float16)s1.w;
            *(half8*)(Zs + e * ZSTR + 64 + q * 16) = o;
            o[0] = (_Float16)s2.x; o[1] = (_Float16)s2.y; o[2] = (_Float16)s2.z; o[3] = (_Float16)s2.w;
            o[4] = (_Float16)s3.x; o[5] = (_Float16)s3.y; o[6] = (_Float16)s3.z; o[7] = (_Float16)s3.w;
            *(half8*)(Zs + e * ZSTR + 64 + q * 16 + 8) = o;
        }
        // ---- wave 0: dst metadata + local-dst-id run scan ----
        if (w == 0) {
            int d = sdst[base + lane];
            dstL[lane] = d;
            eaL[lane] = sea[base + lane];
            int dprev = __shfl_up(d, 1);
            int flag = (lane > 0 && d != dprev) ? 1 : 0;
            int s = flag;
#pragma unroll
            for (int dd = 1; dd < 64; dd <<= 1) {
                int o = __shfl_up(s, dd);
                if (lane >= dd) s += o;
            }
            lidxL[lane] = s;
            if (lane == 0 || flag) dstlist[s] = d;
            if (lane == 63) ndistS = s + 1;
        }
        // ---- zero aggL ----
        {
            float4 z4 = {0.f, 0.f, 0.f, 0.f};
            for (int i = t * 4; i < 64 * ASTR; i += 1024)
                *(float4*)(aggL + i) = z4;
        }
        __syncthreads();   // B1: Z staged, aggL zeroed, lidx ready

        // ---- K-loop: 4 steps x 8 MFMA ----
        floatx4 accf[4], accs[4];
#pragma unroll
        for (int tt = 0; tt < 4; ++tt) {
#pragma unroll
            for (int r = 0; r < 4; ++r) {
                accf[tt][r] = biasf[tt];
                accs[tt][r] = biass[tt];
            }
        }
        const _Float16* zrow = Zs + (w * 16 + l15) * ZSTR;
#pragma unroll
        for (int ks = 0; ks < 4; ++ks) {
            half8 a = *(const half8*)(zrow + ks * 32 + quad * 8);
#pragma unroll
            for (int tt = 0; tt < 4; ++tt) {
                accf[tt] = __builtin_amdgcn_mfma_f32_16x16x32_f16(a, bfrag[tt][ks], accf[tt], 0, 0, 0);
                accs[tt] = __builtin_amdgcn_mfma_f32_16x16x32_f16(a, bfrag[tt + 4][ks], accs[tt], 0, 0, 0);
            }
        }

        // ---- epilogue: ea rank-1 term + activation + LDS aggregation ----
        const int rowbase = w * 16 + quad * 4;
#pragma unroll
        for (int r = 0; r < 4; ++r) {
            float eav = eaL[rowbase + r];
            int lidx = lidxL[rowbase + r];
            float* arow = aggL + lidx * ASTR + l15;
#pragma unroll
            for (int tt = 0; tt < 4; ++tt) {
                float f = accf[tt][r] + eav * wf128[tt];
                float s = accs[tt][r] + eav * ws128[tt];
                float sig = 1.0f / (1.0f + __expf(-f));
                float sp = fmaxf(s, 0.0f) + log1pf(__expf(-fabsf(s)));
                atomicAdd(arow + tt * 16, sig * sp);
            }
        }
        __syncthreads();   // B2: all LDS atomics done

        // ---- flush aggL -> global agg ----
        {
            int nd = ndistS;
            for (int i = t; i < nd * 64; i += 256) {
                int rr = i >> 6, cc = i & 63;
                atomicAdd(agg + dstL[0] * 0 + dstlist[rr] * 64 + cc, aggL[rr * ASTR + cc]);
            }
        }
        __syncthreads();   // B3: flush done before next tile overwrites LDS
    }
}

// ---------------- global mean pool ----------------
__global__ void pool_kernel(const float* __restrict__ h,
                            const int* __restrict__ batch,
                            float* __restrict__ pooled,
                            float* __restrict__ counts) {
    int idx = blockIdx.x * blockDim.x + threadIdx.x;
    if (idx >= NC) return;
    int i = idx >> 6;
    int c = idx & 63;
    int b = batch[i];
    atomicAdd(&pooled[b * CH + c], h[idx]);
    if (c == 0) atomicAdd(&counts[b], 1.0f);
}

// ---------------- head ----------------
__global__ void head_kernel(const float* __restrict__ pooled,
                            const float* __restrict__ counts,
                            const float* __restrict__ W1,
                            const float* __restrict__ b1,
                            const float* __restrict__ W2,
                            const float* __restrict__ b2,
                            float* __restrict__ out) {
    int gph = blockIdx.x;
    int t = threadIdx.x;  // 64
    __shared__ float p[64];
    __shared__ float h1[32];
    float cnt = fmaxf(counts[gph], 1.0f);
    p[t] = pooled[gph * CH + t] / cnt;
    __syncthreads();
    if (t < 32) {
        float acc = b1[t];
#pragma unroll
        for (int c = 0; c < 64; ++c)
            acc = fmaf(p[c], W1[c * 32 + t], acc);
        h1[t] = fmaxf(acc, 0.0f);
    }
    __syncthreads();
    if (t == 0) {
        float acc = b2[0];
#pragma unroll
        for (int j = 0; j < 32; ++j)
            acc = fmaf(h1[j], W2[j], acc);
        out[gph] = acc;
    }
}

extern "C" void kernel_launch(void* const* d_in, const int* in_sizes, int n_in,
                              void* d_out, int out_size, void* d_ws, size_t ws_size,
                              hipStream_t stream) {
    const float* x     = (const float*)d_in[0];
    const int*   ei    = (const int*)d_in[1];
    const float* ea    = (const float*)d_in[2];
    const int*   batch = (const int*)d_in[3];
    const float* W_in  = (const float*)d_in[4];
    const float* b_in  = (const float*)d_in[5];
    const float* g0    = (const float*)d_in[6];
    const float* beta0 = (const float*)d_in[7];

    const float* Wf[3] = {(const float*)d_in[8],  (const float*)d_in[14], (const float*)d_in[20]};
    const float* bfv[3]= {(const float*)d_in[9],  (const float*)d_in[15], (const float*)d_in[21]};
    const float* Wsv[3]= {(const float*)d_in[10], (const float*)d_in[16], (const float*)d_in[22]};
    const float* bsv[3]= {(const float*)d_in[11], (const float*)d_in[17], (const float*)d_in[23]};
    const float* gm[3] = {(const float*)d_in[12], (const float*)d_in[18], (const float*)d_in[24]};
    const float* bb[3] = {(const float*)d_in[13], (const float*)d_in[19], (const float*)d_in[25]};

    const float* W1 = (const float*)d_in[26];
    const float* b1 = (const float*)d_in[27];
    const float* W2 = (const float*)d_in[28];
    const float* b2 = (const float*)d_in[29];

    float* out = (float*)d_out;

    float* ws     = (float*)d_ws;
    float* hA     = ws;                       // [N,64]
    float* hB     = hA + NC;                  // [N,64]
    float* stats  = hB + NC;                  // [128]
    float* ab     = stats + 128;              // [128]
    float* pooled = ab + 128;                 // [G,64]
    float* counts = pooled + N_GRAPHS * CH;   // [G]
    int*   rowptr = (int*)(counts + N_GRAPHS);        // [N+1]
    int*   cursor = rowptr + (N_NODES + 1);           // [N]
    int*   sdst   = cursor + N_NODES;                 // [E]
    int*   ssrc   = sdst + N_EDGES;                   // [E]
    float* sea    = (float*)(ssrc + N_EDGES);         // [E]
    _Float16* WT  = (_Float16*)(sea + N_EDGES);       // 3*[128*128] f16
    float* w128   = (float*)(WT + 3 * 128 * 128);     // 3*[128]
    float* biasL  = w128 + 3 * 128;                   // 3*[128]

    const int elemBlocks = (NC + 255) / 256;
    const int edgeBlocks = (N_EDGES + 255) / 256;

    // ---- sort edges by dst ----
    hipMemsetAsync(rowptr, 0, (N_NODES + 1) * sizeof(int), stream);
    hist_kernel<<<edgeBlocks, 256, 0, stream>>>(ei, rowptr);
    scan_kernel<<<1, 1024, 0, stream>>>(rowptr, cursor);
    scatter_kernel<<<edgeBlocks, 256, 0, stream>>>(ei, ea, cursor, sdst, ssrc, sea);

    // ---- prep f16 transposed weights for the 3 layers ----
    for (int l = 0; l < 3; ++l)
        prep_weights_kernel<<<64, 256, 0, stream>>>(Wf[l], Wsv[l], bfv[l], bsv[l],
                                                    WT + l * 128 * 128, w128 + l * 128,
                                                    biasL + l * 128);

    // ---- input embedding + BN0 + relu ----
    embed_kernel<<<elemBlocks, 256, 0, stream>>>(x, W_in, b_in, hA);
    hipMemsetAsync(stats, 0, 128 * sizeof(float), stream);
    bn_stats_kernel<<<512, 256, 0, stream>>>(hA, stats);
    bn_finalize_kernel<<<1, 64, 0, stream>>>(stats, g0, beta0, ab);
    bn_apply_kernel<true, false><<<elemBlocks, 256, 0, stream>>>(hA, nullptr, ab);

    float* hcur = hA;
    float* hnext = hB;

    for (int l = 0; l < 3; ++l) {
        hipMemsetAsync(hnext, 0, (size_t)NC * sizeof(float), stream);
        hipMemsetAsync(stats, 0, 128 * sizeof(float), stream);
        edge_mfma_kernel<<<512, 256, 0, stream>>>(hcur, sdst, ssrc, sea,
                                                  WT + l * 128 * 128, w128 + l * 128,
                                                  biasL + l * 128, hnext);
        bn_stats_kernel<<<512, 256, 0, stream>>>(hnext, stats);
        bn_finalize_kernel<<<1, 64, 0, stream>>>(stats, gm[l], bb[l], ab);
        if (l < 2)
            bn_apply_kernel<true, true><<<elemBlocks, 256, 0, stream>>>(hnext, hcur, ab);
        else
            bn_apply_kernel<false, true><<<elemBlocks, 256, 0, stream>>>(hnext, hcur, ab);
        float* tmp = hcur; hcur = hnext; hnext = tmp;
    }

    // ---- pool + head ----
    hipMemsetAsync(pooled, 0, (size_t)(N_GRAPHS * CH + N_GRAPHS) * sizeof(float), stream);
    pool_kernel<<<elemBlocks, 256, 0, stream>>>(hcur, batch, pooled, counts);
    head_kernel<<<N_GRAPHS, 64, 0, stream>>>(pooled, counts, W1, b1, W2, b2, out);
}

// Round 4
// 1507.324 us; speedup vs baseline: 8.7184x; 1.5558x over previous
//
#include <hip/hip_runtime.h>
#include <math.h>

#define N_NODES 100000
#define N_EDGES 1200000
#define N_GRAPHS 256
#define CH 64
#define NC (N_NODES * CH)
#define EPS 1e-5f

#define ZSTR 136   // f16 units per Z row (128 + pad), 272B = 17*16B
#define ASTR 65    // f32 units per aggL row
#define NTILES (N_EDGES / 64)

typedef _Float16 half8 __attribute__((ext_vector_type(8)));
typedef float floatx4 __attribute__((ext_vector_type(4)));

// ---------------- embed: out = x @ W_in + b_in ----------------
__global__ void embed_kernel(const float* __restrict__ x,
                             const float* __restrict__ W,   // [12,64]
                             const float* __restrict__ b,   // [64]
                             float* __restrict__ out) {     // [N,64]
    int idx = blockIdx.x * blockDim.x + threadIdx.x;
    if (idx >= NC) return;
    int i = idx >> 6;
    int c = idx & 63;
    const float* xr = x + i * 12;
    float acc = b[c];
#pragma unroll
    for (int k = 0; k < 12; ++k)
        acc = fmaf(xr[k], W[k * CH + c], acc);
    out[idx] = acc;
}

// ---------------- BN stats ----------------
__global__ void bn_stats_kernel(const float* __restrict__ a,
                                float* __restrict__ stats) { // [128] pre-zeroed
    int c = threadIdx.x & 63;
    int sub = threadIdx.x >> 6;
    int rowStart = blockIdx.x * 4 + sub;
    int rowStride = gridDim.x * 4;
    float s = 0.f, q = 0.f;
    for (int r = rowStart; r < N_NODES; r += rowStride) {
        float v = a[r * CH + c];
        s += v;
        q = fmaf(v, v, q);
    }
    __shared__ float ls[4][64];
    __shared__ float lq[4][64];
    ls[sub][c] = s;
    lq[sub][c] = q;
    __syncthreads();
    if (sub == 0) {
        s = ls[0][c] + ls[1][c] + ls[2][c] + ls[3][c];
        q = lq[0][c] + lq[1][c] + lq[2][c] + lq[3][c];
        atomicAdd(&stats[c], s);
        atomicAdd(&stats[64 + c], q);
    }
}

// ---------------- BN finalize ----------------
__global__ void bn_finalize_kernel(const float* __restrict__ stats,
                                   const float* __restrict__ gamma,
                                   const float* __restrict__ beta,
                                   float* __restrict__ ab) { // [128]: A then B
    int c = threadIdx.x; // 64
    float mean = stats[c] * (1.0f / (float)N_NODES);
    float var  = stats[64 + c] * (1.0f / (float)N_NODES) - mean * mean;
    float inv  = rsqrtf(var + EPS);
    float A = gamma[c] * inv;
    ab[c] = A;
    ab[64 + c] = beta[c] - mean * A;
}

// ---------------- BN apply (+residual, +relu), in place; optional f16 copy --
template <bool RELU, bool RES, bool F16OUT>
__global__ void bn_apply_kernel(float* __restrict__ a,
                                const float* __restrict__ res,
                                const float* __restrict__ ab,
                                _Float16* __restrict__ h16) {
    int idx = blockIdx.x * blockDim.x + threadIdx.x;
    if (idx >= NC) return;
    int c = idx & 63;
    float v = fmaf(a[idx], ab[c], ab[64 + c]);
    if (RES) v += res[idx];
    if (RELU) v = fmaxf(v, 0.f);
    a[idx] = v;
    if (F16OUT) h16[idx] = (_Float16)v;
}

// ---------------- counting sort of edges by dst ----------------
__global__ void hist_kernel(const int* __restrict__ ei,
                            int* __restrict__ rowptr) { // [N+1] pre-zeroed
    int e = blockIdx.x * blockDim.x + threadIdx.x;
    if (e < N_EDGES) atomicAdd(&rowptr[ei[N_EDGES + e] + 1], 1);
}

__global__ void scan_kernel(int* __restrict__ a, int* __restrict__ cursor) {
    __shared__ int wsum[16];
    __shared__ int carryS;
    int t = threadIdx.x;           // 1024 threads = 16 waves
    int lane = t & 63, w = t >> 6;
    if (t == 0) carryS = 0;
    __syncthreads();
    for (int base = 0; base <= N_NODES; base += 1024) {
        int i = base + t;
        int v = (i <= N_NODES) ? a[i] : 0;
        int s = v;
#pragma unroll
        for (int d = 1; d < 64; d <<= 1) {
            int o = __shfl_up(s, d);
            if (lane >= d) s += o;
        }
        if (lane == 63) wsum[w] = s;
        __syncthreads();
        if (w == 0) {
            int ws2 = (lane < 16) ? wsum[lane] : 0;
#pragma unroll
            for (int d = 1; d < 16; d <<= 1) {
                int o = __shfl_up(ws2, d);
                if (lane >= d) ws2 += o;
            }
            if (lane < 16) wsum[lane] = ws2;
        }
        __syncthreads();
        int waveoff = (w > 0) ? wsum[w - 1] : 0;
        int total = wsum[15];
        int res = s + waveoff + carryS;
        if (i <= N_NODES) {
            a[i] = res;
            if (i < N_NODES) cursor[i] = res;
        }
        __syncthreads();
        if (t == 0) carryS += total;
        __syncthreads();
    }
}

__global__ void scatter_kernel(const int* __restrict__ ei,
                               const float* __restrict__ ea,
                               int* __restrict__ cursor,
                               int* __restrict__ sdst,
                               int* __restrict__ ssrc,
                               float* __restrict__ sea) {
    int e = blockIdx.x * blockDim.x + threadIdx.x;
    if (e >= N_EDGES) return;
    int d = ei[N_EDGES + e];
    int pos = atomicAdd(&cursor[d], 1);
    sdst[pos] = d;
    ssrc[pos] = ei[e];
    sea[pos] = ea[e];
}

// ---------------- weight prep: WT[n][k] = W[k][n] in f16 ----------------
__global__ void prep_weights_kernel(const float* __restrict__ Wf,  // [129,64]
                                    const float* __restrict__ Ws,  // [129,64]
                                    const float* __restrict__ bf,
                                    const float* __restrict__ bs,
                                    _Float16* __restrict__ WT,     // [128,128]
                                    float* __restrict__ w128,      // [128]
                                    float* __restrict__ bias) {    // [128]
    int idx = blockIdx.x * blockDim.x + threadIdx.x;  // 16384
    if (idx < 128 * 128) {
        int n = idx >> 7;
        int k = idx & 127;
        float v = (n < 64) ? Wf[k * 64 + n] : Ws[k * 64 + (n - 64)];
        WT[idx] = (_Float16)v;
    }
    if (idx < 128) {
        w128[idx] = (idx < 64) ? Wf[128 * 64 + idx] : Ws[128 * 64 + (idx - 64)];
        bias[idx] = (idx < 64) ? bf[idx] : bs[idx - 64];
    }
}

// ---------------- CGConv edge kernel: f16 MFMA, column-split waves ----------
// 256 threads = 4 waves. Wave w owns f-cols [w*16,+16) AND s-cols [w*16,+16),
// computing all 4 row-tiles (64 edges). Weights: 32 VGPRs/wave, loaded once.
// Aggregation: run-merged LDS atomics into aggL, then global flush.
__global__ __launch_bounds__(256, 4)
void edge_mfma_kernel(const _Float16* __restrict__ h16, // [N,64] f16
                      const int* __restrict__ sdst,     // [E] sorted
                      const int* __restrict__ ssrc,
                      const float* __restrict__ sea,
                      const _Float16* __restrict__ WT,  // [128,128]
                      const float* __restrict__ w128,   // [128]
                      const float* __restrict__ bias,   // [128]
                      float* __restrict__ agg) {        // [N,64] pre-zeroed
    __shared__ __align__(16) _Float16 Zs[64 * ZSTR];
    __shared__ __align__(16) float aggL[64 * ASTR];
    __shared__ __align__(16) int dstL[64];
    __shared__ __align__(16) int lidxL[64];
    __shared__ __align__(16) int dstlist[64];
    __shared__ __align__(16) float eaL[64];
    __shared__ int ndistS;

    const int t = threadIdx.x;
    const int lane = t & 63;
    const int w = t >> 6;          // wave 0..3
    const int l15 = lane & 15;
    const int quad = lane >> 4;    // 0..3
    const int col = w * 16 + l15;  // this lane's output column (f and s)

    // ---- one-time: B-fragments for this wave's 16 f-cols + 16 s-cols ----
    half8 wfr[4], wsr[4];
#pragma unroll
    for (int ks = 0; ks < 4; ++ks) {
        wfr[ks] = *(const half8*)(WT + col * 128 + ks * 32 + quad * 8);
        wsr[ks] = *(const half8*)(WT + (64 + col) * 128 + ks * 32 + quad * 8);
    }
    const float biasf = bias[col];
    const float biass = bias[64 + col];
    const float wf128v = w128[col];
    const float ws128v = w128[64 + col];

    for (int tile = blockIdx.x; tile < NTILES; tile += gridDim.x) {
        const int base = tile * 64;

        // ---- stage Z (f16 gather, no converts) ----
        {
            const int e = t >> 2, q = t & 3;
            const _Float16* pd = h16 + (size_t)sdst[base + e] * 64 + q * 16;
            const _Float16* ps = h16 + (size_t)ssrc[base + e] * 64 + q * 16;
            half8 d0 = *(const half8*)(pd);
            half8 d1 = *(const half8*)(pd + 8);
            half8 s0 = *(const half8*)(ps);
            half8 s1 = *(const half8*)(ps + 8);
            *(half8*)(Zs + e * ZSTR + q * 16)          = d0;
            *(half8*)(Zs + e * ZSTR + q * 16 + 8)      = d1;
            *(half8*)(Zs + e * ZSTR + 64 + q * 16)     = s0;
            *(half8*)(Zs + e * ZSTR + 64 + q * 16 + 8) = s1;
        }
        // ---- wave 0: dst metadata + local-dst-id run scan ----
        if (w == 0) {
            int d = sdst[base + lane];
            dstL[lane] = d;
            eaL[lane] = sea[base + lane];
            int dprev = __shfl_up(d, 1);
            int flag = (lane > 0 && d != dprev) ? 1 : 0;
            int s = flag;
#pragma unroll
            for (int dd = 1; dd < 64; dd <<= 1) {
                int o = __shfl_up(s, dd);
                if (lane >= dd) s += o;
            }
            lidxL[lane] = s;
            if (lane == 0 || flag) dstlist[s] = d;
            if (lane == 63) ndistS = s + 1;
        }
        // ---- zero aggL ----
        {
            float4 z4 = {0.f, 0.f, 0.f, 0.f};
            for (int i = t * 4; i < 64 * ASTR; i += 1024)
                *(float4*)(aggL + i) = z4;
        }
        __syncthreads();   // B1

        // ---- K-loop: 4 steps x (4 rt x 2) MFMA ----
        floatx4 accf[4], accs[4];
#pragma unroll
        for (int rt = 0; rt < 4; ++rt) {
#pragma unroll
            for (int r = 0; r < 4; ++r) {
                accf[rt][r] = biasf;
                accs[rt][r] = biass;
            }
        }
#pragma unroll
        for (int ks = 0; ks < 4; ++ks) {
#pragma unroll
            for (int rt = 0; rt < 4; ++rt) {
                half8 a = *(const half8*)(Zs + (rt * 16 + l15) * ZSTR + ks * 32 + quad * 8);
                accf[rt] = __builtin_amdgcn_mfma_f32_16x16x32_f16(a, wfr[ks], accf[rt], 0, 0, 0);
                accs[rt] = __builtin_amdgcn_mfma_f32_16x16x32_f16(a, wsr[ks], accs[rt], 0, 0, 0);
            }
        }

        // ---- epilogue: ea rank-1 + fast activation + run-merged LDS agg ----
#pragma unroll
        for (int rt = 0; rt < 4; ++rt) {
            const int row0 = rt * 16 + quad * 4;
            float4 ea4 = *(const float4*)(eaL + row0);
            int4 li4 = *(const int4*)(lidxL + row0);
            float eav[4] = {ea4.x, ea4.y, ea4.z, ea4.w};
            int lidx[4] = {li4.x, li4.y, li4.z, li4.w};
            float pend = 0.0f;
            int plidx = lidx[0];
#pragma unroll
            for (int r = 0; r < 4; ++r) {
                float f = fmaf(eav[r], wf128v, accf[rt][r]);
                float s = fmaf(eav[r], ws128v, accs[rt][r]);
                float sig = __builtin_amdgcn_rcpf(1.0f + __expf(-f));
                float sp = fmaxf(s, 0.0f) + __logf(1.0f + __expf(-fabsf(s)));
                float m = sig * sp;
                if (lidx[r] != plidx) {
                    atomicAdd(aggL + plidx * ASTR + col, pend);
                    pend = 0.0f;
                    plidx = lidx[r];
                }
                pend += m;
            }
            atomicAdd(aggL + plidx * ASTR + col, pend);
        }
        __syncthreads();   // B2

        // ---- flush aggL -> global agg ----
        {
            int nd = ndistS;
            for (int i = t; i < nd * 64; i += 256) {
                int rr = i >> 6, cc = i & 63;
                atomicAdd(agg + (size_t)dstlist[rr] * 64 + cc, aggL[rr * ASTR + cc]);
            }
        }
        __syncthreads();   // B3
    }
}

// ---------------- global mean pool ----------------
__global__ void pool_kernel(const float* __restrict__ h,
                            const int* __restrict__ batch,
                            float* __restrict__ pooled,
                            float* __restrict__ counts) {
    int idx = blockIdx.x * blockDim.x + threadIdx.x;
    if (idx >= NC) return;
    int i = idx >> 6;
    int c = idx & 63;
    int b = batch[i];
    atomicAdd(&pooled[b * CH + c], h[idx]);
    if (c == 0) atomicAdd(&counts[b], 1.0f);
}

// ---------------- head ----------------
__global__ void head_kernel(const float* __restrict__ pooled,
                            const float* __restrict__ counts,
                            const float* __restrict__ W1,
                            const float* __restrict__ b1,
                            const float* __restrict__ W2,
                            const float* __restrict__ b2,
                            float* __restrict__ out) {
    int gph = blockIdx.x;
    int t = threadIdx.x;  // 64
    __shared__ float p[64];
    __shared__ float h1[32];
    float cnt = fmaxf(counts[gph], 1.0f);
    p[t] = pooled[gph * CH + t] / cnt;
    __syncthreads();
    if (t < 32) {
        float acc = b1[t];
#pragma unroll
        for (int c = 0; c < 64; ++c)
            acc = fmaf(p[c], W1[c * 32 + t], acc);
        h1[t] = fmaxf(acc, 0.0f);
    }
    __syncthreads();
    if (t == 0) {
        float acc = b2[0];
#pragma unroll
        for (int j = 0; j < 32; ++j)
            acc = fmaf(h1[j], W2[j], acc);
        out[gph] = acc;
    }
}

extern "C" void kernel_launch(void* const* d_in, const int* in_sizes, int n_in,
                              void* d_out, int out_size, void* d_ws, size_t ws_size,
                              hipStream_t stream) {
    const float* x     = (const float*)d_in[0];
    const int*   ei    = (const int*)d_in[1];
    const float* ea    = (const float*)d_in[2];
    const int*   batch = (const int*)d_in[3];
    const float* W_in  = (const float*)d_in[4];
    const float* b_in  = (const float*)d_in[5];
    const float* g0    = (const float*)d_in[6];
    const float* beta0 = (const float*)d_in[7];

    const float* Wf[3] = {(const float*)d_in[8],  (const float*)d_in[14], (const float*)d_in[20]};
    const float* bfv[3]= {(const float*)d_in[9],  (const float*)d_in[15], (const float*)d_in[21]};
    const float* Wsv[3]= {(const float*)d_in[10], (const float*)d_in[16], (const float*)d_in[22]};
    const float* bsv[3]= {(const float*)d_in[11], (const float*)d_in[17], (const float*)d_in[23]};
    const float* gm[3] = {(const float*)d_in[12], (const float*)d_in[18], (const float*)d_in[24]};
    const float* bb[3] = {(const float*)d_in[13], (const float*)d_in[19], (const float*)d_in[25]};

    const float* W1 = (const float*)d_in[26];
    const float* b1 = (const float*)d_in[27];
    const float* W2 = (const float*)d_in[28];
    const float* b2 = (const float*)d_in[29];

    float* out = (float*)d_out;

    float* ws     = (float*)d_ws;
    float* hA     = ws;                       // [N,64]
    float* hB     = hA + NC;                  // [N,64]
    float* stats  = hB + NC;                  // [128]
    float* ab     = stats + 128;              // [128]
    float* pooled = ab + 128;                 // [G,64]
    float* counts = pooled + N_GRAPHS * CH;   // [G]
    int*   rowptr = (int*)(counts + N_GRAPHS);        // [N+1]
    int*   cursor = rowptr + (N_NODES + 1);           // [N]
    int*   sdst   = cursor + N_NODES;                 // [E]
    int*   ssrc   = sdst + N_EDGES;                   // [E]
    float* sea    = (float*)(ssrc + N_EDGES);         // [E]
    _Float16* WT  = (_Float16*)(sea + N_EDGES);       // 3*[128*128] f16
    float* w128   = (float*)(WT + 3 * 128 * 128);     // 3*[128]
    float* biasL  = w128 + 3 * 128;                   // 3*[128]
    _Float16* h16 = (_Float16*)(biasL + 3 * 128);     // [N,64] f16

    const int elemBlocks = (NC + 255) / 256;
    const int edgeBlocks = (N_EDGES + 255) / 256;

    // ---- sort edges by dst ----
    hipMemsetAsync(rowptr, 0, (N_NODES + 1) * sizeof(int), stream);
    hist_kernel<<<edgeBlocks, 256, 0, stream>>>(ei, rowptr);
    scan_kernel<<<1, 1024, 0, stream>>>(rowptr, cursor);
    scatter_kernel<<<edgeBlocks, 256, 0, stream>>>(ei, ea, cursor, sdst, ssrc, sea);

    // ---- prep f16 transposed weights ----
    for (int l = 0; l < 3; ++l)
        prep_weights_kernel<<<64, 256, 0, stream>>>(Wf[l], Wsv[l], bfv[l], bsv[l],
                                                    WT + l * 128 * 128, w128 + l * 128,
                                                    biasL + l * 128);

    // ---- input embedding + BN0 + relu (+f16 copy) ----
    embed_kernel<<<elemBlocks, 256, 0, stream>>>(x, W_in, b_in, hA);
    hipMemsetAsync(stats, 0, 128 * sizeof(float), stream);
    bn_stats_kernel<<<512, 256, 0, stream>>>(hA, stats);
    bn_finalize_kernel<<<1, 64, 0, stream>>>(stats, g0, beta0, ab);
    bn_apply_kernel<true, false, true><<<elemBlocks, 256, 0, stream>>>(hA, nullptr, ab, h16);

    float* hcur = hA;
    float* hnext = hB;

    for (int l = 0; l < 3; ++l) {
        hipMemsetAsync(hnext, 0, (size_t)NC * sizeof(float), stream);
        hipMemsetAsync(stats, 0, 128 * sizeof(float), stream);
        edge_mfma_kernel<<<1024, 256, 0, stream>>>(h16, sdst, ssrc, sea,
                                                   WT + l * 128 * 128, w128 + l * 128,
                                                   biasL + l * 128, hnext);
        bn_stats_kernel<<<512, 256, 0, stream>>>(hnext, stats);
        bn_finalize_kernel<<<1, 64, 0, stream>>>(stats, gm[l], bb[l], ab);
        if (l < 2)
            bn_apply_kernel<true, true, true><<<elemBlocks, 256, 0, stream>>>(hnext, hcur, ab, h16);
        else
            bn_apply_kernel<false, true, false><<<elemBlocks, 256, 0, stream>>>(hnext, hcur, ab, nullptr);
        float* tmp = hcur; hcur = hnext; hnext = tmp;
    }

    // ---- pool + head ----
    hipMemsetAsync(pooled, 0, (size_t)(N_GRAPHS * CH + N_GRAPHS) * sizeof(float), stream);
    pool_kernel<<<elemBlocks, 256, 0, stream>>>(hcur, batch, pooled, counts);
    head_kernel<<<N_GRAPHS, 64, 0, stream>>>(pooled, counts, W1, b1, W2, b2, out);
}

// Round 5
// 1140.519 us; speedup vs baseline: 11.5223x; 1.3216x over previous
//
#include <hip/hip_runtime.h>
#include <math.h>

#define N_NODES 100000
#define N_EDGES 1200000
#define N_GRAPHS 256
#define CH 64
#define NC (N_NODES * CH)
#define EPS 1e-5f

#define ZSTR 136   // f16 units per Z row (128 + pad), 272B = 17*16B
#define ASTR 65    // f32 units per aggL row
#define NTILES (N_EDGES / 64)

typedef _Float16 half8 __attribute__((ext_vector_type(8)));
typedef float floatx4 __attribute__((ext_vector_type(4)));

// ---------------- embed: out = x @ W_in + b_in ----------------
__global__ void embed_kernel(const float* __restrict__ x,
                             const float* __restrict__ W,   // [12,64]
                             const float* __restrict__ b,   // [64]
                             float* __restrict__ out) {     // [N,64]
    int idx = blockIdx.x * blockDim.x + threadIdx.x;
    if (idx >= NC) return;
    int i = idx >> 6;
    int c = idx & 63;
    const float* xr = x + i * 12;
    float acc = b[c];
#pragma unroll
    for (int k = 0; k < 12; ++k)
        acc = fmaf(xr[k], W[k * CH + c], acc);
    out[idx] = acc;
}

// ---------------- BN stats ----------------
__global__ void bn_stats_kernel(const float* __restrict__ a,
                                float* __restrict__ stats) { // [128] pre-zeroed
    int c = threadIdx.x & 63;
    int sub = threadIdx.x >> 6;
    int rowStart = blockIdx.x * 4 + sub;
    int rowStride = gridDim.x * 4;
    float s = 0.f, q = 0.f;
    for (int r = rowStart; r < N_NODES; r += rowStride) {
        float v = a[r * CH + c];
        s += v;
        q = fmaf(v, v, q);
    }
    __shared__ float ls[4][64];
    __shared__ float lq[4][64];
    ls[sub][c] = s;
    lq[sub][c] = q;
    __syncthreads();
    if (sub == 0) {
        s = ls[0][c] + ls[1][c] + ls[2][c] + ls[3][c];
        q = lq[0][c] + lq[1][c] + lq[2][c] + lq[3][c];
        atomicAdd(&stats[c], s);
        atomicAdd(&stats[64 + c], q);
    }
}

// ---------------- BN finalize ----------------
__global__ void bn_finalize_kernel(const float* __restrict__ stats,
                                   const float* __restrict__ gamma,
                                   const float* __restrict__ beta,
                                   float* __restrict__ ab) { // [128]: A then B
    int c = threadIdx.x; // 64
    float mean = stats[c] * (1.0f / (float)N_NODES);
    float var  = stats[64 + c] * (1.0f / (float)N_NODES) - mean * mean;
    float inv  = rsqrtf(var + EPS);
    float A = gamma[c] * inv;
    ab[c] = A;
    ab[64 + c] = beta[c] - mean * A;
}

// ---------------- BN apply (+residual, +relu), in place; optional f16 copy --
template <bool RELU, bool RES, bool F16OUT>
__global__ void bn_apply_kernel(float* __restrict__ a,
                                const float* __restrict__ res,
                                const float* __restrict__ ab,
                                _Float16* __restrict__ h16) {
    int idx = blockIdx.x * blockDim.x + threadIdx.x;
    if (idx >= NC) return;
    int c = idx & 63;
    float v = fmaf(a[idx], ab[c], ab[64 + c]);
    if (RES) v += res[idx];
    if (RELU) v = fmaxf(v, 0.f);
    a[idx] = v;
    if (F16OUT) h16[idx] = (_Float16)v;
}

// ---------------- counting sort of edges by dst ----------------
__global__ void hist_kernel(const int* __restrict__ ei,
                            int* __restrict__ rowptr) { // [N+1] pre-zeroed
    int e = blockIdx.x * blockDim.x + threadIdx.x;
    if (e < N_EDGES) atomicAdd(&rowptr[ei[N_EDGES + e] + 1], 1);
}

__global__ void scan_kernel(int* __restrict__ a, int* __restrict__ cursor) {
    __shared__ int wsum[16];
    __shared__ int carryS;
    int t = threadIdx.x;           // 1024 threads = 16 waves
    int lane = t & 63, w = t >> 6;
    if (t == 0) carryS = 0;
    __syncthreads();
    for (int base = 0; base <= N_NODES; base += 1024) {
        int i = base + t;
        int v = (i <= N_NODES) ? a[i] : 0;
        int s = v;
#pragma unroll
        for (int d = 1; d < 64; d <<= 1) {
            int o = __shfl_up(s, d);
            if (lane >= d) s += o;
        }
        if (lane == 63) wsum[w] = s;
        __syncthreads();
        if (w == 0) {
            int ws2 = (lane < 16) ? wsum[lane] : 0;
#pragma unroll
            for (int d = 1; d < 16; d <<= 1) {
                int o = __shfl_up(ws2, d);
                if (lane >= d) ws2 += o;
            }
            if (lane < 16) wsum[lane] = ws2;
        }
        __syncthreads();
        int waveoff = (w > 0) ? wsum[w - 1] : 0;
        int total = wsum[15];
        int res = s + waveoff + carryS;
        if (i <= N_NODES) {
            a[i] = res;
            if (i < N_NODES) cursor[i] = res;
        }
        __syncthreads();
        if (t == 0) carryS += total;
        __syncthreads();
    }
}

__global__ void scatter_kernel(const int* __restrict__ ei,
                               const float* __restrict__ ea,
                               int* __restrict__ cursor,
                               int* __restrict__ sdst,
                               int* __restrict__ ssrc,
                               float* __restrict__ sea) {
    int e = blockIdx.x * blockDim.x + threadIdx.x;
    if (e >= N_EDGES) return;
    int d = ei[N_EDGES + e];
    int pos = atomicAdd(&cursor[d], 1);
    sdst[pos] = d;
    ssrc[pos] = ei[e];
    sea[pos] = ea[e];
}

// ---------------- weight prep: WT[n][k] = W[k][n] in f16 ----------------
__global__ void prep_weights_kernel(const float* __restrict__ Wf,  // [129,64]
                                    const float* __restrict__ Ws,  // [129,64]
                                    const float* __restrict__ bf,
                                    const float* __restrict__ bs,
                                    _Float16* __restrict__ WT,     // [128,128]
                                    float* __restrict__ w128,      // [128]
                                    float* __restrict__ bias) {    // [128]
    int idx = blockIdx.x * blockDim.x + threadIdx.x;  // 16384
    if (idx < 128 * 128) {
        int n = idx >> 7;
        int k = idx & 127;
        float v = (n < 64) ? Wf[k * 64 + n] : Ws[k * 64 + (n - 64)];
        WT[idx] = (_Float16)v;
    }
    if (idx < 128) {
        w128[idx] = (idx < 64) ? Wf[128 * 64 + idx] : Ws[128 * 64 + (idx - 64)];
        bias[idx] = (idx < 64) ? bf[idx] : bs[idx - 64];
    }
}

// ---------------- CGConv edge kernel: f16 MFMA, column-split waves ----------
__global__ __launch_bounds__(256, 4)
void edge_mfma_kernel(const _Float16* __restrict__ h16, // [N,64] f16
                      const int* __restrict__ sdst,     // [E] sorted
                      const int* __restrict__ ssrc,
                      const float* __restrict__ sea,
                      const _Float16* __restrict__ WT,  // [128,128]
                      const float* __restrict__ w128,   // [128]
                      const float* __restrict__ bias,   // [128]
                      float* __restrict__ agg) {        // [N,64] pre-zeroed
    __shared__ __align__(16) _Float16 Zs[64 * ZSTR];
    __shared__ __align__(16) float aggL[64 * ASTR];
    __shared__ __align__(16) int dstL[64];
    __shared__ __align__(16) int lidxL[64];
    __shared__ __align__(16) int dstlist[64];
    __shared__ __align__(16) float eaL[64];
    __shared__ int ndistS;

    const int t = threadIdx.x;
    const int lane = t & 63;
    const int w = t >> 6;          // wave 0..3
    const int l15 = lane & 15;
    const int quad = lane >> 4;    // 0..3
    const int col = w * 16 + l15;  // this lane's output column (f and s)

    half8 wfr[4], wsr[4];
#pragma unroll
    for (int ks = 0; ks < 4; ++ks) {
        wfr[ks] = *(const half8*)(WT + col * 128 + ks * 32 + quad * 8);
        wsr[ks] = *(const half8*)(WT + (64 + col) * 128 + ks * 32 + quad * 8);
    }
    const float biasf = bias[col];
    const float biass = bias[64 + col];
    const float wf128v = w128[col];
    const float ws128v = w128[64 + col];

    for (int tile = blockIdx.x; tile < NTILES; tile += gridDim.x) {
        const int base = tile * 64;

        // ---- stage Z (f16 gather, no converts) ----
        {
            const int e = t >> 2, q = t & 3;
            const _Float16* pd = h16 + (size_t)sdst[base + e] * 64 + q * 16;
            const _Float16* ps = h16 + (size_t)ssrc[base + e] * 64 + q * 16;
            half8 d0 = *(const half8*)(pd);
            half8 d1 = *(const half8*)(pd + 8);
            half8 s0 = *(const half8*)(ps);
            half8 s1 = *(const half8*)(ps + 8);
            *(half8*)(Zs + e * ZSTR + q * 16)          = d0;
            *(half8*)(Zs + e * ZSTR + q * 16 + 8)      = d1;
            *(half8*)(Zs + e * ZSTR + 64 + q * 16)     = s0;
            *(half8*)(Zs + e * ZSTR + 64 + q * 16 + 8) = s1;
        }
        if (w == 0) {
            int d = sdst[base + lane];
            dstL[lane] = d;
            eaL[lane] = sea[base + lane];
            int dprev = __shfl_up(d, 1);
            int flag = (lane > 0 && d != dprev) ? 1 : 0;
            int s = flag;
#pragma unroll
            for (int dd = 1; dd < 64; dd <<= 1) {
                int o = __shfl_up(s, dd);
                if (lane >= dd) s += o;
            }
            lidxL[lane] = s;
            if (lane == 0 || flag) dstlist[s] = d;
            if (lane == 63) ndistS = s + 1;
        }
        {
            float4 z4 = {0.f, 0.f, 0.f, 0.f};
            for (int i = t * 4; i < 64 * ASTR; i += 1024)
                *(float4*)(aggL + i) = z4;
        }
        __syncthreads();   // B1

        floatx4 accf[4], accs[4];
#pragma unroll
        for (int rt = 0; rt < 4; ++rt) {
#pragma unroll
            for (int r = 0; r < 4; ++r) {
                accf[rt][r] = biasf;
                accs[rt][r] = biass;
            }
        }
#pragma unroll
        for (int ks = 0; ks < 4; ++ks) {
#pragma unroll
            for (int rt = 0; rt < 4; ++rt) {
                half8 a = *(const half8*)(Zs + (rt * 16 + l15) * ZSTR + ks * 32 + quad * 8);
                accf[rt] = __builtin_amdgcn_mfma_f32_16x16x32_f16(a, wfr[ks], accf[rt], 0, 0, 0);
                accs[rt] = __builtin_amdgcn_mfma_f32_16x16x32_f16(a, wsr[ks], accs[rt], 0, 0, 0);
            }
        }

#pragma unroll
        for (int rt = 0; rt < 4; ++rt) {
            const int row0 = rt * 16 + quad * 4;
            float4 ea4 = *(const float4*)(eaL + row0);
            int4 li4 = *(const int4*)(lidxL + row0);
            float eav[4] = {ea4.x, ea4.y, ea4.z, ea4.w};
            int lidx[4] = {li4.x, li4.y, li4.z, li4.w};
            float pend = 0.0f;
            int plidx = lidx[0];
#pragma unroll
            for (int r = 0; r < 4; ++r) {
                float f = fmaf(eav[r], wf128v, accf[rt][r]);
                float s = fmaf(eav[r], ws128v, accs[rt][r]);
                float sig = __builtin_amdgcn_rcpf(1.0f + __expf(-f));
                float sp = fmaxf(s, 0.0f) + __logf(1.0f + __expf(-fabsf(s)));
                float m = sig * sp;
                if (lidx[r] != plidx) {
                    atomicAdd(aggL + plidx * ASTR + col, pend);
                    pend = 0.0f;
                    plidx = lidx[r];
                }
                pend += m;
            }
            atomicAdd(aggL + plidx * ASTR + col, pend);
        }
        __syncthreads();   // B2

        {
            int nd = ndistS;
            for (int i = t; i < nd * 64; i += 256) {
                int rr = i >> 6, cc = i & 63;
                atomicAdd(agg + (size_t)dstlist[rr] * 64 + cc, aggL[rr * ASTR + cc]);
            }
        }
        __syncthreads();   // B3
    }
}

// ---------------- global mean pool: segmented walkers over sorted batch ------
// 4 walkers/block x 64 channels. Walker owns contiguous row range; running
// per-channel sum flushed once per batch-run boundary (sorted batch => ~1
// flush per walker + per graph crossing). Replaces 6.4M contended atomics
// with ~85k spread ones.
#define POOL_BLOCKS 256
__global__ __launch_bounds__(256)
void pool_kernel(const float* __restrict__ h,
                 const int* __restrict__ batch,
                 float* __restrict__ pooled,   // [G,64] pre-zeroed
                 float* __restrict__ counts) { // [G]   pre-zeroed
    const int c = threadIdx.x & 63;
    const int walker = blockIdx.x * 4 + (threadIdx.x >> 6);
    const int nwalk = POOL_BLOCKS * 4;
    const int chunk = (N_NODES + nwalk - 1) / nwalk;
    int r0 = walker * chunk;
    int r1 = min(N_NODES, r0 + chunk);
    if (r0 >= r1) return;

    int cur = batch[r0];
    float acc = 0.0f;
    int runlen = 0;
    for (int r = r0; r < r1; ++r) {
        int b = batch[r];
        if (b != cur) {
            atomicAdd(&pooled[cur * CH + c], acc);
            if (c == 0) atomicAdd(&counts[cur], (float)runlen);
            acc = 0.0f;
            runlen = 0;
            cur = b;
        }
        acc += h[(size_t)r * CH + c];
        ++runlen;
    }
    atomicAdd(&pooled[cur * CH + c], acc);
    if (c == 0) atomicAdd(&counts[cur], (float)runlen);
}

// ---------------- head ----------------
__global__ void head_kernel(const float* __restrict__ pooled,
                            const float* __restrict__ counts,
                            const float* __restrict__ W1,
                            const float* __restrict__ b1,
                            const float* __restrict__ W2,
                            const float* __restrict__ b2,
                            float* __restrict__ out) {
    int gph = blockIdx.x;
    int t = threadIdx.x;  // 64
    __shared__ float p[64];
    __shared__ float h1[32];
    float cnt = fmaxf(counts[gph], 1.0f);
    p[t] = pooled[gph * CH + t] / cnt;
    __syncthreads();
    if (t < 32) {
        float acc = b1[t];
#pragma unroll
        for (int c = 0; c < 64; ++c)
            acc = fmaf(p[c], W1[c * 32 + t], acc);
        h1[t] = fmaxf(acc, 0.0f);
    }
    __syncthreads();
    if (t == 0) {
        float acc = b2[0];
#pragma unroll
        for (int j = 0; j < 32; ++j)
            acc = fmaf(h1[j], W2[j], acc);
        out[gph] = acc;
    }
}

extern "C" void kernel_launch(void* const* d_in, const int* in_sizes, int n_in,
                              void* d_out, int out_size, void* d_ws, size_t ws_size,
                              hipStream_t stream) {
    const float* x     = (const float*)d_in[0];
    const int*   ei    = (const int*)d_in[1];
    const float* ea    = (const float*)d_in[2];
    const int*   batch = (const int*)d_in[3];
    const float* W_in  = (const float*)d_in[4];
    const float* b_in  = (const float*)d_in[5];
    const float* g0    = (const float*)d_in[6];
    const float* beta0 = (const float*)d_in[7];

    const float* Wf[3] = {(const float*)d_in[8],  (const float*)d_in[14], (const float*)d_in[20]};
    const float* bfv[3]= {(const float*)d_in[9],  (const float*)d_in[15], (const float*)d_in[21]};
    const float* Wsv[3]= {(const float*)d_in[10], (const float*)d_in[16], (const float*)d_in[22]};
    const float* bsv[3]= {(const float*)d_in[11], (const float*)d_in[17], (const float*)d_in[23]};
    const float* gm[3] = {(const float*)d_in[12], (const float*)d_in[18], (const float*)d_in[24]};
    const float* bb[3] = {(const float*)d_in[13], (const float*)d_in[19], (const float*)d_in[25]};

    const float* W1 = (const float*)d_in[26];
    const float* b1 = (const float*)d_in[27];
    const float* W2 = (const float*)d_in[28];
    const float* b2 = (const float*)d_in[29];

    float* out = (float*)d_out;

    float* ws     = (float*)d_ws;
    float* hA     = ws;                       // [N,64]
    float* hB     = hA + NC;                  // [N,64]
    float* stats  = hB + NC;                  // [128]
    float* ab     = stats + 128;              // [128]
    float* pooled = ab + 128;                 // [G,64]
    float* counts = pooled + N_GRAPHS * CH;   // [G]
    int*   rowptr = (int*)(counts + N_GRAPHS);        // [N+1]
    int*   cursor = rowptr + (N_NODES + 1);           // [N]
    int*   sdst   = cursor + N_NODES;                 // [E]
    int*   ssrc   = sdst + N_EDGES;                   // [E]
    float* sea    = (float*)(ssrc + N_EDGES);         // [E]
    _Float16* WT  = (_Float16*)(sea + N_EDGES);       // 3*[128*128] f16
    float* w128   = (float*)(WT + 3 * 128 * 128);     // 3*[128]
    float* biasL  = w128 + 3 * 128;                   // 3*[128]
    _Float16* h16 = (_Float16*)(biasL + 3 * 128);     // [N,64] f16

    const int elemBlocks = (NC + 255) / 256;
    const int edgeBlocks = (N_EDGES + 255) / 256;

    // ---- sort edges by dst ----
    hipMemsetAsync(rowptr, 0, (N_NODES + 1) * sizeof(int), stream);
    hist_kernel<<<edgeBlocks, 256, 0, stream>>>(ei, rowptr);
    scan_kernel<<<1, 1024, 0, stream>>>(rowptr, cursor);
    scatter_kernel<<<edgeBlocks, 256, 0, stream>>>(ei, ea, cursor, sdst, ssrc, sea);

    // ---- prep f16 transposed weights ----
    for (int l = 0; l < 3; ++l)
        prep_weights_kernel<<<64, 256, 0, stream>>>(Wf[l], Wsv[l], bfv[l], bsv[l],
                                                    WT + l * 128 * 128, w128 + l * 128,
                                                    biasL + l * 128);

    // ---- input embedding + BN0 + relu (+f16 copy) ----
    embed_kernel<<<elemBlocks, 256, 0, stream>>>(x, W_in, b_in, hA);
    hipMemsetAsync(stats, 0, 128 * sizeof(float), stream);
    bn_stats_kernel<<<512, 256, 0, stream>>>(hA, stats);
    bn_finalize_kernel<<<1, 64, 0, stream>>>(stats, g0, beta0, ab);
    bn_apply_kernel<true, false, true><<<elemBlocks, 256, 0, stream>>>(hA, nullptr, ab, h16);

    float* hcur = hA;
    float* hnext = hB;

    for (int l = 0; l < 3; ++l) {
        hipMemsetAsync(hnext, 0, (size_t)NC * sizeof(float), stream);
        hipMemsetAsync(stats, 0, 128 * sizeof(float), stream);
        edge_mfma_kernel<<<1024, 256, 0, stream>>>(h16, sdst, ssrc, sea,
                                                   WT + l * 128 * 128, w128 + l * 128,
                                                   biasL + l * 128, hnext);
        bn_stats_kernel<<<512, 256, 0, stream>>>(hnext, stats);
        bn_finalize_kernel<<<1, 64, 0, stream>>>(stats, gm[l], bb[l], ab);
        if (l < 2)
            bn_apply_kernel<true, true, true><<<elemBlocks, 256, 0, stream>>>(hnext, hcur, ab, h16);
        else
            bn_apply_kernel<false, true, false><<<elemBlocks, 256, 0, stream>>>(hnext, hcur, ab, nullptr);
        float* tmp = hcur; hcur = hnext; hnext = tmp;
    }

    // ---- pool + head ----
    hipMemsetAsync(pooled, 0, (size_t)(N_GRAPHS * CH + N_GRAPHS) * sizeof(float), stream);
    pool_kernel<<<POOL_BLOCKS, 256, 0, stream>>>(hcur, batch, pooled, counts);
    head_kernel<<<N_GRAPHS, 64, 0, stream>>>(pooled, counts, W1, b1, W2, b2, out);
}